// Round 3
// baseline (79.293 us; speedup 1.0000x reference)
//
#include <hip/hip_runtime.h>
#include <math.h>

#define NB 32
#define NPTS 200000
#define N4 (NPTS / 4)
#define THREADS 256
#define IMG_W_C 1280.0f
#define IMG_H_C 384.0f

// Build M = K @ [R|t]  (3x4, row-major) from quaternion q, translation t, intrinsics K (3x3)
__device__ inline void make_mat(const float* __restrict__ q4, const float* __restrict__ t3,
                                const float* __restrict__ K9, float* M) {
    float qw = q4[0], qx = q4[1], qy = q4[2], qz = q4[3];
    float inv = 1.0f / sqrtf(qw * qw + qx * qx + qy * qy + qz * qz);
    qw *= inv; qx *= inv; qy *= inv; qz *= inv;
    float R[9];
    R[0] = 1.f - 2.f * (qy * qy + qz * qz); R[1] = 2.f * (qx * qy - qz * qw); R[2] = 2.f * (qx * qz + qy * qw);
    R[3] = 2.f * (qx * qy + qz * qw); R[4] = 1.f - 2.f * (qx * qx + qz * qz); R[5] = 2.f * (qy * qz - qx * qw);
    R[6] = 2.f * (qx * qz - qy * qw); R[7] = 2.f * (qy * qz + qx * qw); R[8] = 1.f - 2.f * (qx * qx + qy * qy);
    for (int i = 0; i < 3; i++) {
        float k0 = K9[i * 3 + 0], k1 = K9[i * 3 + 1], k2 = K9[i * 3 + 2];
        M[i * 4 + 0] = k0 * R[0] + k1 * R[3] + k2 * R[6];
        M[i * 4 + 1] = k0 * R[1] + k1 * R[4] + k2 * R[7];
        M[i * 4 + 2] = k0 * R[2] + k1 * R[5] + k2 * R[8];
        M[i * 4 + 3] = k0 * t3[0] + k1 * t3[1] + k2 * t3[2];
    }
}

__device__ inline void point_contrib(const float* __restrict__ mg, const float* __restrict__ mp,
                                     float cx, float cy, float x, float y, float z,
                                     float& sw, float& se) {
    float g0 = fmaf(mg[0], x, fmaf(mg[1], y, fmaf(mg[2], z, mg[3])));
    float g1 = fmaf(mg[4], x, fmaf(mg[5], y, fmaf(mg[6], z, mg[7])));
    float g2 = fmaf(mg[8], x, fmaf(mg[9], y, fmaf(mg[10], z, mg[11])));
    float p0 = fmaf(mp[0], x, fmaf(mp[1], y, fmaf(mp[2], z, mp[3])));
    float p1 = fmaf(mp[4], x, fmaf(mp[5], y, fmaf(mp[6], z, mp[7])));
    float p2 = fmaf(mp[8], x, fmaf(mp[9], y, fmaf(mp[10], z, mp[11])));
    float ig = __builtin_amdgcn_rcpf(g2), ip = __builtin_amdgcn_rcpf(p2);
    float Fg = g0 * ig, Sg = g1 * ig;
    float F1 = p0 * ip, S1 = p1 * ip;

    // Exact collapse of the reference's 8-select chain:
    //   dF = (0<Fg<W && 0<F1<W) ? Fg-F1 : 0  (min-form), dS analog with H.
    float mF = fminf(fminf(Fg, F1), fminf(IMG_W_C - Fg, IMG_W_C - F1));
    float mS = fminf(fminf(Sg, S1), fminf(IMG_H_C - Sg, IMG_H_C - S1));
    float dF = (mF > 0.f) ? (Fg - F1) : 0.f;
    float dS = (mS > 0.f) ? (Sg - S1) : 0.f;

    float dx = Fg - cx, dy = Sg - cy;
    float rw = __builtin_amdgcn_rsqf(fmaf(dx, dx, dy * dy));   // raw w, always > 0
    sw += rw;
    se = fmaf(__builtin_amdgcn_sqrtf(fmaf(dF, dF, dS * dS)), rw, se);
}

template<int BPB>
__global__ __launch_bounds__(THREADS)
void fused_loss(const float* __restrict__ pc,
                const float* __restrict__ tgt_t, const float* __restrict__ tgt_r,
                const float* __restrict__ err_t, const float* __restrict__ err_r,
                const float* __restrict__ cam,
                float* __restrict__ partial /* [2 * NB * BPB] */,
                unsigned int* __restrict__ ticket,
                float* __restrict__ out) {
    const int b  = blockIdx.x / BPB;
    const int cb = blockIdx.x % BPB;

    __shared__ float sM[26];
    if (threadIdx.x == 0) {
        float Mg[12], Mp[12];
        make_mat(tgt_r + b * 4, tgt_t + b * 3, cam + b * 9, Mg);
        make_mat(err_r + b * 4, err_t + b * 3, cam + b * 9, Mp);
        #pragma unroll
        for (int i = 0; i < 12; i++) { sM[i] = Mg[i]; sM[12 + i] = Mp[i]; }
        sM[24] = cam[b * 9 + 2];  // cx
        sM[25] = cam[b * 9 + 5];  // cy
    }
    __syncthreads();

    float mg[12], mp[12];
    #pragma unroll
    for (int i = 0; i < 12; i++) { mg[i] = sM[i]; mp[i] = sM[12 + i]; }
    const float cx = sM[24], cy = sM[25];

    // point_clouds layout (B, 4, N): planes x,y,z contiguous in n; plane 3 is all-ones (skipped).
    const float4* __restrict__ Xp = (const float4*)(pc + (size_t)b * 4 * NPTS);
    const float4* __restrict__ Yp = (const float4*)(pc + (size_t)b * 4 * NPTS + NPTS);
    const float4* __restrict__ Zp = (const float4*)(pc + (size_t)b * 4 * NPTS + 2 * NPTS);

    float sum_w = 0.f, sum_e = 0.f;
    constexpr int STRIDE = BPB * THREADS;   // compile-time
    int i = cb * THREADS + threadIdx.x;
    // Software-pipelined: issue next iteration's loads before computing current.
    float4 xv = Xp[i], yv = Yp[i], zv = Zp[i];
    for (;;) {
        const int inext = i + STRIDE;
        const bool more = inext < N4;
        float4 xn, yn, zn;
        if (more) { xn = Xp[inext]; yn = Yp[inext]; zn = Zp[inext]; }
        point_contrib(mg, mp, cx, cy, xv.x, yv.x, zv.x, sum_w, sum_e);
        point_contrib(mg, mp, cx, cy, xv.y, yv.y, zv.y, sum_w, sum_e);
        point_contrib(mg, mp, cx, cy, xv.z, yv.z, zv.z, sum_w, sum_e);
        point_contrib(mg, mp, cx, cy, xv.w, yv.w, zv.w, sum_w, sum_e);
        if (!more) break;
        xv = xn; yv = yn; zv = zn; i = inext;
    }

    // wave (64-lane) reduction, then cross-wave via LDS
    #pragma unroll
    for (int off = 32; off > 0; off >>= 1) {
        sum_w += __shfl_down(sum_w, off);
        sum_e += __shfl_down(sum_e, off);
    }
    __shared__ float red[2][THREADS / 64];
    const int wave = threadIdx.x >> 6, lane = threadIdx.x & 63;
    if (lane == 0) { red[0][wave] = sum_w; red[1][wave] = sum_e; }
    __syncthreads();

    __shared__ unsigned int sIsLast;
    if (threadIdx.x == 0) {
        float sw = 0.f, se = 0.f;
        #pragma unroll
        for (int k = 0; k < THREADS / 64; k++) { sw += red[0][k]; se += red[1][k]; }
        partial[blockIdx.x] = sw;
        partial[NB * BPB + blockIdx.x] = se;
        __threadfence();  // make partials visible device-wide before the ticket
        unsigned int old = atomicAdd(ticket, 1u);
        // Modulo ticket: works from ANY initial value (incl. 0xAA poison) and
        // self-consistent across graph replays (grows by gridDim.x per call).
        sIsLast = ((old + 1u) % (unsigned int)gridDim.x == 0u) ? 1u : 0u;
    }
    __syncthreads();
    if (!sIsLast) return;

    // ---- Last block: finalize all batches ----
    __threadfence();  // acquire: see all other blocks' partials
    const int bb = threadIdx.x;
    float val = 0.f;
    if (bb < NB) {
        float sw = 0.f, se = 0.f;
        for (int k = 0; k < BPB; k++) {
            sw += partial[bb * BPB + k];
            se += partial[NB * BPB + bb * BPB + k];
        }
        float pc_b = se / fmaxf(sw, 5.0f) * (1.0f / NPTS);

        // smooth-L1 translation loss
        float lt = 0.f;
        #pragma unroll
        for (int c = 0; c < 3; c++) {
            float d = err_t[bb * 3 + c] - tgt_t[bb * 3 + c];
            float ad = fabsf(d);
            lt += (ad < 1.0f) ? 0.5f * d * d : (ad - 0.5f);
        }

        // quaternion distance
        float qw = err_r[bb * 4], qx = err_r[bb * 4 + 1], qy = err_r[bb * 4 + 2], qz = err_r[bb * 4 + 3];
        float rn = 1.0f / sqrtf(qw * qw + qx * qx + qy * qy + qz * qz);
        qw *= rn; qx *= rn; qy *= rn; qz *= rn;
        float rw_ = tgt_r[bb * 4], rx = tgt_r[bb * 4 + 1], ry = tgt_r[bb * 4 + 2], rz = tgt_r[bb * 4 + 3];
        float rn2 = 1.0f / sqrtf(rw_ * rw_ + rx * rx + ry * ry + rz * rz);
        rw_ *= rn2; rx = -rx * rn2; ry = -ry * rn2; rz = -rz * rn2;  // r^-1
        float dw = qw * rw_ - qx * rx - qy * ry - qz * rz;
        float dx = qw * rx + qx * rw_ + qy * rz - qz * ry;
        float dy = qw * ry - qx * rz + qy * rw_ + qz * rx;
        float dz = qw * rz + qx * ry - qy * rx + qz * rw_;
        float lr = 2.0f * atan2f(sqrtf(dx * dx + dy * dy + dz * dz), fabsf(dw));

        val = 0.5f * (lr + lt) + 0.5f * pc_b;   // RESCALE=1, WEIGHT_PC=0.5
    }
    #pragma unroll
    for (int off = 32; off > 0; off >>= 1) val += __shfl_down(val, off);
    if (threadIdx.x == 0) out[0] = val * (1.0f / NB);
}

extern "C" void kernel_launch(void* const* d_in, const int* in_sizes, int n_in,
                              void* d_out, int out_size, void* d_ws, size_t ws_size,
                              hipStream_t stream) {
    const float* pc    = (const float*)d_in[0];
    const float* tgt_t = (const float*)d_in[1];
    const float* tgt_r = (const float*)d_in[2];
    const float* err_t = (const float*)d_in[3];
    const float* err_r = (const float*)d_in[4];
    const float* cam   = (const float*)d_in[5];
    float* out = (float*)d_out;

    unsigned int* ticket = (unsigned int*)d_ws;                 // persists across replays; modulo scheme
    float* partial = (float*)((char*)d_ws + 64);                // [2 * NB * BPB]

    const size_t need64 = 64 + (size_t)2 * NB * 64 * sizeof(float);
    if (ws_size >= need64) {
        fused_loss<64><<<NB * 64, THREADS, 0, stream>>>(pc, tgt_t, tgt_r, err_t, err_r, cam, partial, ticket, out);
    } else {
        fused_loss<32><<<NB * 32, THREADS, 0, stream>>>(pc, tgt_t, tgt_r, err_t, err_r, cam, partial, ticket, out);
    }
}

// Round 4
// 29.690 us; speedup vs baseline: 2.6707x; 2.6707x over previous
//
#include <hip/hip_runtime.h>
#include <math.h>

#define NB 32
#define NPTS 200000
#define N4 (NPTS / 4)
#define THREADS 256
#define IMG_W_C 1280.0f
#define IMG_H_C 384.0f

// Build M = K @ [R|t]  (3x4, row-major) from quaternion q, translation t, intrinsics K (3x3).
// Called per-thread so the result lives in VGPRs (NOT LDS — R3 showed the compiler
// will otherwise re-read LDS for every FMA and collapse to 32 VGPRs, 4x slowdown).
__device__ inline void make_mat(const float* __restrict__ q4, const float* __restrict__ t3,
                                const float* __restrict__ K9, float* M) {
    float qw = q4[0], qx = q4[1], qy = q4[2], qz = q4[3];
    float inv = 1.0f / sqrtf(qw * qw + qx * qx + qy * qy + qz * qz);
    qw *= inv; qx *= inv; qy *= inv; qz *= inv;
    float R[9];
    R[0] = 1.f - 2.f * (qy * qy + qz * qz); R[1] = 2.f * (qx * qy - qz * qw); R[2] = 2.f * (qx * qz + qy * qw);
    R[3] = 2.f * (qx * qy + qz * qw); R[4] = 1.f - 2.f * (qx * qx + qz * qz); R[5] = 2.f * (qy * qz - qx * qw);
    R[6] = 2.f * (qx * qz - qy * qw); R[7] = 2.f * (qy * qz + qx * qw); R[8] = 1.f - 2.f * (qx * qx + qy * qy);
    #pragma unroll
    for (int i = 0; i < 3; i++) {
        float k0 = K9[i * 3 + 0], k1 = K9[i * 3 + 1], k2 = K9[i * 3 + 2];
        M[i * 4 + 0] = k0 * R[0] + k1 * R[3] + k2 * R[6];
        M[i * 4 + 1] = k0 * R[1] + k1 * R[4] + k2 * R[7];
        M[i * 4 + 2] = k0 * R[2] + k1 * R[5] + k2 * R[8];
        M[i * 4 + 3] = k0 * t3[0] + k1 * t3[1] + k2 * t3[2];
    }
}

__device__ inline void point_contrib(const float* __restrict__ mg, const float* __restrict__ mp,
                                     float cx, float cy, float x, float y, float z,
                                     float& sw, float& se) {
    float g0 = fmaf(mg[0], x, fmaf(mg[1], y, fmaf(mg[2], z, mg[3])));
    float g1 = fmaf(mg[4], x, fmaf(mg[5], y, fmaf(mg[6], z, mg[7])));
    float g2 = fmaf(mg[8], x, fmaf(mg[9], y, fmaf(mg[10], z, mg[11])));
    float p0 = fmaf(mp[0], x, fmaf(mp[1], y, fmaf(mp[2], z, mp[3])));
    float p1 = fmaf(mp[4], x, fmaf(mp[5], y, fmaf(mp[6], z, mp[7])));
    float p2 = fmaf(mp[8], x, fmaf(mp[9], y, fmaf(mp[10], z, mp[11])));
    float ig = __builtin_amdgcn_rcpf(g2), ip = __builtin_amdgcn_rcpf(p2);
    float Fg = g0 * ig, Sg = g1 * ig;
    float F1 = p0 * ip, S1 = p1 * ip;

    // Exact collapse of the reference's 8-select chain:
    //   dF = (0<Fg<W && 0<F1<W) ? Fg-F1 : 0  (min-form), dS analog with H.
    float mF = fminf(fminf(Fg, F1), fminf(IMG_W_C - Fg, IMG_W_C - F1));
    float mS = fminf(fminf(Sg, S1), fminf(IMG_H_C - Sg, IMG_H_C - S1));
    float dF = (mF > 0.f) ? (Fg - F1) : 0.f;
    float dS = (mS > 0.f) ? (Sg - S1) : 0.f;

    float dx = Fg - cx, dy = Sg - cy;
    float rw = __builtin_amdgcn_rsqf(fmaf(dx, dx, dy * dy));   // raw w, always > 0
    sw += rw;
    se = fmaf(__builtin_amdgcn_sqrtf(fmaf(dF, dF, dS * dS)), rw, se);
}

template<int BPB>
__global__ __launch_bounds__(THREADS)
void pc_partial(const float* __restrict__ pc,
                const float* __restrict__ tgt_t, const float* __restrict__ tgt_r,
                const float* __restrict__ err_t, const float* __restrict__ err_r,
                const float* __restrict__ cam,
                float* __restrict__ partial /* [2 * NB * BPB] */) {
    const int b  = blockIdx.x / BPB;
    const int cb = blockIdx.x % BPB;

    // Per-thread matrix build: ~60 flops, keeps mg/mp in VGPRs.
    float mg[12], mp[12];
    make_mat(tgt_r + b * 4, tgt_t + b * 3, cam + b * 9, mg);
    make_mat(err_r + b * 4, err_t + b * 3, cam + b * 9, mp);
    const float cx = cam[b * 9 + 2];
    const float cy = cam[b * 9 + 5];

    // point_clouds layout (B, 4, N): planes x,y,z contiguous in n; plane 3 is all-ones (skipped).
    const float4* __restrict__ Xp = (const float4*)(pc + (size_t)b * 4 * NPTS);
    const float4* __restrict__ Yp = (const float4*)(pc + (size_t)b * 4 * NPTS + NPTS);
    const float4* __restrict__ Zp = (const float4*)(pc + (size_t)b * 4 * NPTS + 2 * NPTS);

    float sum_w = 0.f, sum_e = 0.f;
    constexpr int STRIDE = BPB * THREADS;
    for (int i = cb * THREADS + threadIdx.x; i < N4; i += STRIDE) {
        float4 xv = Xp[i], yv = Yp[i], zv = Zp[i];
        point_contrib(mg, mp, cx, cy, xv.x, yv.x, zv.x, sum_w, sum_e);
        point_contrib(mg, mp, cx, cy, xv.y, yv.y, zv.y, sum_w, sum_e);
        point_contrib(mg, mp, cx, cy, xv.z, yv.z, zv.z, sum_w, sum_e);
        point_contrib(mg, mp, cx, cy, xv.w, yv.w, zv.w, sum_w, sum_e);
    }

    // wave (64-lane) reduction, then cross-wave via LDS
    #pragma unroll
    for (int off = 32; off > 0; off >>= 1) {
        sum_w += __shfl_down(sum_w, off);
        sum_e += __shfl_down(sum_e, off);
    }
    __shared__ float red[2][THREADS / 64];
    const int wave = threadIdx.x >> 6, lane = threadIdx.x & 63;
    if (lane == 0) { red[0][wave] = sum_w; red[1][wave] = sum_e; }
    __syncthreads();
    if (threadIdx.x == 0) {
        float sw = 0.f, se = 0.f;
        #pragma unroll
        for (int k = 0; k < THREADS / 64; k++) { sw += red[0][k]; se += red[1][k]; }
        partial[blockIdx.x] = sw;
        partial[NB * BPB + blockIdx.x] = se;
    }
}

__global__ __launch_bounds__(64)
void finalize(const float* __restrict__ tgt_t, const float* __restrict__ tgt_r,
              const float* __restrict__ err_t, const float* __restrict__ err_r,
              const float* __restrict__ partial, float* __restrict__ out, int bpb) {
    const int b = threadIdx.x;
    float val = 0.f;
    if (b < NB) {
        float sw = 0.f, se = 0.f;
        for (int i = 0; i < bpb; i++) {
            sw += partial[b * bpb + i];
            se += partial[NB * bpb + b * bpb + i];
        }
        float pc_b = se / fmaxf(sw, 5.0f) * (1.0f / NPTS);

        // smooth-L1 translation loss
        float lt = 0.f;
        #pragma unroll
        for (int c = 0; c < 3; c++) {
            float d = err_t[b * 3 + c] - tgt_t[b * 3 + c];
            float ad = fabsf(d);
            lt += (ad < 1.0f) ? 0.5f * d * d : (ad - 0.5f);
        }

        // quaternion distance
        float qw = err_r[b * 4], qx = err_r[b * 4 + 1], qy = err_r[b * 4 + 2], qz = err_r[b * 4 + 3];
        float rn = 1.0f / sqrtf(qw * qw + qx * qx + qy * qy + qz * qz);
        qw *= rn; qx *= rn; qy *= rn; qz *= rn;
        float rw_ = tgt_r[b * 4], rx = tgt_r[b * 4 + 1], ry = tgt_r[b * 4 + 2], rz = tgt_r[b * 4 + 3];
        float rn2 = 1.0f / sqrtf(rw_ * rw_ + rx * rx + ry * ry + rz * rz);
        rw_ *= rn2; rx = -rx * rn2; ry = -ry * rn2; rz = -rz * rn2;  // r^-1
        float dw = qw * rw_ - qx * rx - qy * ry - qz * rz;
        float dx = qw * rx + qx * rw_ + qy * rz - qz * ry;
        float dy = qw * ry - qx * rz + qy * rw_ + qz * rx;
        float dz = qw * rz + qx * ry - qy * rx + qz * rw_;
        float lr = 2.0f * atan2f(sqrtf(dx * dx + dy * dy + dz * dz), fabsf(dw));

        val = 0.5f * (lr + lt) + 0.5f * pc_b;   // RESCALE=1, WEIGHT_PC=0.5
    }
    #pragma unroll
    for (int off = 32; off > 0; off >>= 1) val += __shfl_down(val, off);
    if (threadIdx.x == 0) out[0] = val * (1.0f / NB);
}

extern "C" void kernel_launch(void* const* d_in, const int* in_sizes, int n_in,
                              void* d_out, int out_size, void* d_ws, size_t ws_size,
                              hipStream_t stream) {
    const float* pc    = (const float*)d_in[0];
    const float* tgt_t = (const float*)d_in[1];
    const float* tgt_r = (const float*)d_in[2];
    const float* err_t = (const float*)d_in[3];
    const float* err_r = (const float*)d_in[4];
    const float* cam   = (const float*)d_in[5];
    float* partial = (float*)d_ws;
    float* out = (float*)d_out;

    const int bpb = (ws_size >= (size_t)(2 * NB * 64 * sizeof(float))) ? 64 : 32;
    if (bpb == 64) {
        pc_partial<64><<<NB * 64, THREADS, 0, stream>>>(pc, tgt_t, tgt_r, err_t, err_r, cam, partial);
    } else {
        pc_partial<32><<<NB * 32, THREADS, 0, stream>>>(pc, tgt_t, tgt_r, err_t, err_r, cam, partial);
    }
    finalize<<<1, 64, 0, stream>>>(tgt_t, tgt_r, err_t, err_r, partial, out, bpb);
}